// Round 1
// baseline (363.289 us; speedup 1.0000x reference)
//
#include <hip/hip_runtime.h>

// FeatureAttentionLayer: B=64, NF=256, W=128, E=128, K=32 — ALL FP32.
#define NFEAT 256
#define TK    32
#define WIN   128
#define EMB   128
#define NBATCH 64
#define ALPHA 0.2f
#define MROWS (NBATCH * NFEAT)   // 16384 rows of Wx

typedef float f32x4 __attribute__((ext_vector_type(4)));

__device__ __forceinline__ float lrelu(float x) { return x > 0.f ? x : ALPHA * x; }

// ---------------------------------------------------------------------------
// Kernel 1: Wx = x @ W + b  (M=16384, K=128, N=128), fp32 VALU.
// Block: 256 thr, 32 rows. x-tile transposed into LDS (pad 36 floats: rows
// 16B-aligned, conflict-free b128 reads). Thread (g=t>>5, ct=t&31) computes
// rows g*4..g*4+3 x cols ct*4..ct*4+3 with a 4x4 register tile.
// Epilogue: s1[row]=<Wx[row],a[0:128]>, s2[row]=<Wx[row],a[128:256]>
// reduced across the 32 ct-lanes (half-wave) via shfl_xor.
// (unchanged from verified 312 µs version)
// ---------------------------------------------------------------------------
__global__ __launch_bounds__(256) void gemm_wx(
    const float* __restrict__ x,      // 16384 x 128
    const float* __restrict__ W,      // 128 x 128 (row-major [k][n])
    const float* __restrict__ bn,     // 128
    const float* __restrict__ avec,   // 256
    float* __restrict__ wx,           // out: 16384 x 128
    float* __restrict__ s1, float* __restrict__ s2) {
  __shared__ float xT[WIN][36];      // [k][r], padded
  int t = threadIdx.x;
  int rows0 = blockIdx.x * 32;

  // ---- stage x tile transposed: thread t -> row r=t>>3, cols (t&7)*16..+15
  {
    int r = t >> 3, jc = t & 7;
    const float4* src = (const float4*)(x + (long)(rows0 + r) * WIN + jc * 16);
#pragma unroll
    for (int u = 0; u < 4; ++u) {
      float4 v = src[u];
      int c = jc * 16 + u * 4;
      xT[c + 0][r] = v.x; xT[c + 1][r] = v.y; xT[c + 2][r] = v.z; xT[c + 3][r] = v.w;
    }
  }
  __syncthreads();

  int g = t >> 5, ct = t & 31;
  int r0 = g * 4;                    // local rows r0..r0+3
  int c0 = ct * 4;                   // cols c0..c0+3

  float acc[4][4];
#pragma unroll
  for (int i = 0; i < 4; ++i)
#pragma unroll
    for (int j = 0; j < 4; ++j) acc[i][j] = 0.f;

#pragma unroll 4
  for (int k = 0; k < WIN; ++k) {
    float4 xv = *(const float4*)&xT[k][r0];
    float4 wv = *(const float4*)(W + k * EMB + c0);
    acc[0][0] += xv.x * wv.x; acc[0][1] += xv.x * wv.y; acc[0][2] += xv.x * wv.z; acc[0][3] += xv.x * wv.w;
    acc[1][0] += xv.y * wv.x; acc[1][1] += xv.y * wv.y; acc[1][2] += xv.y * wv.z; acc[1][3] += xv.y * wv.w;
    acc[2][0] += xv.z * wv.x; acc[2][1] += xv.z * wv.y; acc[2][2] += xv.z * wv.z; acc[2][3] += xv.z * wv.w;
    acc[3][0] += xv.w * wv.x; acc[3][1] += xv.w * wv.y; acc[3][2] += xv.w * wv.z; acc[3][3] += xv.w * wv.w;
  }

  // + b_n
  float4 bv = *(const float4*)(bn + c0);
#pragma unroll
  for (int i = 0; i < 4; ++i) {
    acc[i][0] += bv.x; acc[i][1] += bv.y; acc[i][2] += bv.z; acc[i][3] += bv.w;
  }

  // store Wx (coalesced float4 per 32-lane group) — cached: k2 gathers reuse it
#pragma unroll
  for (int i = 0; i < 4; ++i) {
    float4 o = make_float4(acc[i][0], acc[i][1], acc[i][2], acc[i][3]);
    *(float4*)(wx + (long)(rows0 + r0 + i) * EMB + c0) = o;
  }

  // s1/s2 epilogue
  float4 a1 = *(const float4*)(avec + c0);
  float4 a2 = *(const float4*)(avec + EMB + c0);
  float p1[4], p2[4];
#pragma unroll
  for (int i = 0; i < 4; ++i) {
    p1[i] = acc[i][0] * a1.x + acc[i][1] * a1.y + acc[i][2] * a1.z + acc[i][3] * a1.w;
    p2[i] = acc[i][0] * a2.x + acc[i][1] * a2.y + acc[i][2] * a2.z + acc[i][3] * a2.w;
  }
#pragma unroll
  for (int i = 0; i < 4; ++i) {
#pragma unroll
    for (int m = 1; m < 32; m <<= 1) {
      p1[i] += __shfl_xor(p1[i], m, 64);
      p2[i] += __shfl_xor(p2[i], m, 64);
    }
  }
  if (ct == 0) {
#pragma unroll
    for (int i = 0; i < 4; ++i) {
      s1[rows0 + r0 + i] = p1[i];
      s2[rows0 + r0 + i] = p2[i];
    }
  }
}

// ---------------------------------------------------------------------------
// Kernel 2 (restructured): 2048 blocks = 256 CU x 8 blocks x 4 waves — one
// full-occupancy round, no tail. Each block owns (b, 8 consecutive n).
// Phase 1: all 256 threads active — thread (nl=t>>5, k=t&31) computes one
//   e-value; softmax reduce via 32-wide shfl_xor (stays within wave halves).
// Phase 2: block writes a CONTIGUOUS 128 KB slab of out with nontemporal
//   float4 stores (each wave = contiguous 2 KB line), keeping wx hot in L2.
//
// e[k<16]  = lrelu(s1[b,n] + s2[b,n]) + nan_to_num(bias[n,k])
// e[k>=16] = lrelu(s1[b,nbr[n,2k-32]] + s2[b,nbr[n,2k-31]]) + ...
// h[b,n,k,:] = lrelu(softmax_k(e)[k] * Wx[b, nbr[n,k], :])
// ---------------------------------------------------------------------------
__global__ __launch_bounds__(256) void attn_out(
    const int* __restrict__ edge,      // row 0 of edge_indices: 256*32 ints
    const float* __restrict__ biasn,   // 256*32
    const float* __restrict__ wx,      // 16384 x 128
    const float* __restrict__ s1, const float* __restrict__ s2,
    float* __restrict__ out) {
  __shared__ float att[8][TK];
  __shared__ int nbrS[8][TK];
  int bidx = blockIdx.x;               // 0..2047
  int b  = bidx >> 5;                  // 0..63
  int n0 = (bidx & 31) << 3;           // first of 8 n's
  int tid = threadIdx.x;
  int k  = tid & 31;
  int nl = tid >> 5;                   // 0..7
  int n  = n0 + nl;

  // ---- phase 1: one thread per (n,k) e-value
  nbrS[nl][k] = edge[n * TK + k];
  float v;
  if (k < 16) {
    v = s1[b * NFEAT + n] + s2[b * NFEAT + n];
  } else {
    int j0 = 2 * k - 32;
    int r0 = edge[n * TK + j0];
    int r1 = edge[n * TK + j0 + 1];
    v = s1[b * NFEAT + r0] + s2[b * NFEAT + r1];
  }
  v = lrelu(v);
  float bb = biasn[n * TK + k];
  if (bb != bb) bb = 0.f;              // nan_to_num
  v += bb;
  float mx = v;
#pragma unroll
  for (int m = 1; m < 32; m <<= 1) mx = fmaxf(mx, __shfl_xor(mx, m, 64));
  float ex = __expf(v - mx);
  float sum = ex;
#pragma unroll
  for (int m = 1; m < 32; m <<= 1) sum += __shfl_xor(sum, m, 64);
  att[nl][k] = ex / sum;
  __syncthreads();

  // ---- phase 2: stream 8 n's x 32 k-rows x 128 floats = 128 KB contiguous
  int kk = tid >> 4;                   // 0..15
  int c0 = (tid & 15) * 8;             // 8 floats per thread per row
  const long wrow_base = (long)b * NFEAT;
  float* oblk = out + ((long)(b * NFEAT + n0)) * TK * EMB;
#pragma unroll 2
  for (int nn = 0; nn < 8; ++nn) {
#pragma unroll
    for (int p = 0; p < 2; ++p) {
      int k2 = kk + p * 16;
      float ak = att[nn][k2];
      long row = wrow_base + nbrS[nn][k2];
      const f32x4* src = (const f32x4*)(wx + row * EMB + c0);
      f32x4 v0 = src[0], v1 = src[1];
      f32x4 o0, o1;
      o0.x = lrelu(ak * v0.x); o0.y = lrelu(ak * v0.y);
      o0.z = lrelu(ak * v0.z); o0.w = lrelu(ak * v0.w);
      o1.x = lrelu(ak * v1.x); o1.y = lrelu(ak * v1.y);
      o1.z = lrelu(ak * v1.z); o1.w = lrelu(ak * v1.w);
      f32x4* dst = (f32x4*)(oblk + ((long)nn * TK + k2) * EMB + c0);
      __builtin_nontemporal_store(o0, dst);
      __builtin_nontemporal_store(o1, dst + 1);
    }
  }
}

extern "C" void kernel_launch(void* const* d_in, const int* in_sizes, int n_in,
                              void* d_out, int out_size, void* d_ws, size_t ws_size,
                              hipStream_t stream) {
  const float* x_n    = (const float*)d_in[0];
  // d_in[1] x_e: unused by reference
  const int*   edge   = (const int*)d_in[2];
  // d_in[3] all_embeddings: unused by reference
  const float* W_n    = (const float*)d_in[4];
  const float* b_n    = (const float*)d_in[5];
  const float* a_v    = (const float*)d_in[6];
  const float* bias_n = (const float*)d_in[7];
  float* out = (float*)d_out;

  char* ws = (char*)d_ws;
  float* wx = (float*)ws;                                   // 8 MB
  float* s1 = (float*)(ws + (8 << 20));                     // 64 KB
  float* s2 = (float*)(ws + (8 << 20) + (64 << 10));        // 64 KB

  gemm_wx<<<MROWS / 32, 256, 0, stream>>>(x_n, W_n, b_n, a_v, wx, s1, s2);
  attn_out<<<NBATCH * NFEAT / 8, 256, 0, stream>>>(edge, bias_n, wx, s1, s2, out);
}

// Round 2
// 313.825 us; speedup vs baseline: 1.1576x; 1.1576x over previous
//
#include <hip/hip_runtime.h>

// FeatureAttentionLayer: B=64, NF=256, W=128, E=128, K=32 — ALL FP32.
#define NFEAT 256
#define TK    32
#define WIN   128
#define EMB   128
#define NBATCH 64
#define ALPHA 0.2f
#define MROWS (NBATCH * NFEAT)   // 16384 rows of Wx

__device__ __forceinline__ float lrelu(float x) { return x > 0.f ? x : ALPHA * x; }

// ---------------------------------------------------------------------------
// Kernel 1: Wx = x @ W + b  (M=16384, K=128, N=128), fp32 VALU.
// R2 change: 16 rows/block (was 32) -> 1024 blocks = 4 blocks/CU = 4 waves/SIMD
// (was 2), doubling latency hiding at identical instruction count.
// Block: 256 thr. x-tile transposed into LDS xT[128][18] (pad 18: float2 reads
// stay 8B-aligned; one-time staging writes are 8-way, negligible).
// Thread (g=t>>5, ct=t&31) computes rows g*2..g*2+1 x cols ct*4..ct*4+3.
// Epilogue: s1[row]=<Wx[row],a[0:128]>, s2[row]=<Wx[row],a[128:256]>
// reduced across the 32 ct-lanes (half-wave) via shfl_xor.
// ---------------------------------------------------------------------------
__global__ __launch_bounds__(256) void gemm_wx(
    const float* __restrict__ x,      // 16384 x 128
    const float* __restrict__ W,      // 128 x 128 (row-major [k][n])
    const float* __restrict__ bn,     // 128
    const float* __restrict__ avec,   // 256
    float* __restrict__ wx,           // out: 16384 x 128
    float* __restrict__ s1, float* __restrict__ s2) {
  __shared__ float xT[WIN][18];      // [k][r], 16 rows + 2 pad
  int t = threadIdx.x;
  int rows0 = blockIdx.x * 16;

  // ---- stage x tile transposed: thread t -> row r=t>>4, cols (t&15)*8..+7
  {
    int r = t >> 4, jc = t & 15;
    const float4* src = (const float4*)(x + (long)(rows0 + r) * WIN + jc * 8);
#pragma unroll
    for (int u = 0; u < 2; ++u) {
      float4 v = src[u];
      int c = jc * 8 + u * 4;
      xT[c + 0][r] = v.x; xT[c + 1][r] = v.y; xT[c + 2][r] = v.z; xT[c + 3][r] = v.w;
    }
  }
  __syncthreads();

  int g = t >> 5, ct = t & 31;
  int r0 = g * 2;                    // local rows r0, r0+1
  int c0 = ct * 4;                   // cols c0..c0+3

  float acc[2][4];
#pragma unroll
  for (int i = 0; i < 2; ++i)
#pragma unroll
    for (int j = 0; j < 4; ++j) acc[i][j] = 0.f;

#pragma unroll 4
  for (int k = 0; k < WIN; ++k) {
    float2 xv = *(const float2*)&xT[k][r0];
    float4 wv = *(const float4*)(W + k * EMB + c0);
    acc[0][0] += xv.x * wv.x; acc[0][1] += xv.x * wv.y; acc[0][2] += xv.x * wv.z; acc[0][3] += xv.x * wv.w;
    acc[1][0] += xv.y * wv.x; acc[1][1] += xv.y * wv.y; acc[1][2] += xv.y * wv.z; acc[1][3] += xv.y * wv.w;
  }

  // + b_n
  float4 bv = *(const float4*)(bn + c0);
#pragma unroll
  for (int i = 0; i < 2; ++i) {
    acc[i][0] += bv.x; acc[i][1] += bv.y; acc[i][2] += bv.z; acc[i][3] += bv.w;
  }

  // store Wx (coalesced float4 per 32-lane group)
#pragma unroll
  for (int i = 0; i < 2; ++i) {
    float4 o = make_float4(acc[i][0], acc[i][1], acc[i][2], acc[i][3]);
    *(float4*)(wx + (long)(rows0 + r0 + i) * EMB + c0) = o;
  }

  // s1/s2 epilogue
  float4 a1 = *(const float4*)(avec + c0);
  float4 a2 = *(const float4*)(avec + EMB + c0);
  float p1[2], p2[2];
#pragma unroll
  for (int i = 0; i < 2; ++i) {
    p1[i] = acc[i][0] * a1.x + acc[i][1] * a1.y + acc[i][2] * a1.z + acc[i][3] * a1.w;
    p2[i] = acc[i][0] * a2.x + acc[i][1] * a2.y + acc[i][2] * a2.z + acc[i][3] * a2.w;
  }
#pragma unroll
  for (int i = 0; i < 2; ++i) {
#pragma unroll
    for (int m = 1; m < 32; m <<= 1) {
      p1[i] += __shfl_xor(p1[i], m, 64);
      p2[i] += __shfl_xor(p2[i], m, 64);
    }
  }
  if (ct == 0) {
#pragma unroll
    for (int i = 0; i < 2; ++i) {
      s1[rows0 + r0 + i] = p1[i];
      s2[rows0 + r0 + i] = p2[i];
    }
  }
}

// ---------------------------------------------------------------------------
// Kernel 2: per (b,n): softmax over 32 k + streamed fp32 output.
// (reverted verbatim to the round-0 structure that measured 312 µs —
//  the 8-n/nontemporal restructure regressed to 363 µs)
// e[k<16]  = lrelu(s1[b,n] + s2[b,n]) + bias[n,k]
// e[k>=16] = lrelu(s1[b,nbr[n,2k-32]] + s2[b,nbr[n,2k-31]]) + bias[n,k]
// h[b,n,k,:] = lrelu(softmax_k(e)[k] * Wx[b, nbr[n,k], :])
// ---------------------------------------------------------------------------
__global__ __launch_bounds__(256) void attn_out(
    const int* __restrict__ edge,      // row 0 of edge_indices: 256*32 ints
    const float* __restrict__ biasn,   // 256*32
    const float* __restrict__ wx,      // 16384 x 128
    const float* __restrict__ s1, const float* __restrict__ s2,
    float* __restrict__ out) {
  __shared__ float att[TK];
  __shared__ int nbrS[TK];
  int bidx = blockIdx.x;
  int b = bidx >> 8, n = bidx & 255;
  int tid = threadIdx.x;

  if (tid < TK) {
    int k = tid;
    nbrS[k] = edge[n * TK + k];
    float v;
    if (k < 16) {
      v = s1[b * NFEAT + n] + s2[b * NFEAT + n];
    } else {
      int j0 = 2 * k - 32;
      int r0 = edge[n * TK + j0];
      int r1 = edge[n * TK + j0 + 1];
      v = s1[b * NFEAT + r0] + s2[b * NFEAT + r1];
    }
    v = lrelu(v);
    float bb = biasn[n * TK + k];
    if (bb != bb) bb = 0.f;            // nan_to_num
    v += bb;
    float mx = v;
#pragma unroll
    for (int m = 1; m < 32; m <<= 1) mx = fmaxf(mx, __shfl_xor(mx, m, 64));
    float ex = __expf(v - mx);
    float sum = ex;
#pragma unroll
    for (int m = 1; m < 32; m <<= 1) sum += __shfl_xor(sum, m, 64);
    att[k] = ex / sum;
  }
  __syncthreads();

  // 16 threads per k-row, 8 floats (2 float4) each; 2 passes over k.
#pragma unroll
  for (int p = 0; p < 2; ++p) {
    int k = (tid >> 4) + p * 16;
    int c0 = (tid & 15) * 8;
    long row = (long)b * NFEAT + nbrS[k];
    float ak = att[k];
    const float4* src = (const float4*)(wx + row * EMB + c0);
    float4 v0 = src[0], v1 = src[1];
    float4 o0 = make_float4(lrelu(ak * v0.x), lrelu(ak * v0.y), lrelu(ak * v0.z), lrelu(ak * v0.w));
    float4 o1 = make_float4(lrelu(ak * v1.x), lrelu(ak * v1.y), lrelu(ak * v1.z), lrelu(ak * v1.w));
    float4* dst = (float4*)(out + ((long)bidx * TK + k) * EMB + c0);
    dst[0] = o0; dst[1] = o1;
  }
}

extern "C" void kernel_launch(void* const* d_in, const int* in_sizes, int n_in,
                              void* d_out, int out_size, void* d_ws, size_t ws_size,
                              hipStream_t stream) {
  const float* x_n    = (const float*)d_in[0];
  // d_in[1] x_e: unused by reference
  const int*   edge   = (const int*)d_in[2];
  // d_in[3] all_embeddings: unused by reference
  const float* W_n    = (const float*)d_in[4];
  const float* b_n    = (const float*)d_in[5];
  const float* a_v    = (const float*)d_in[6];
  const float* bias_n = (const float*)d_in[7];
  float* out = (float*)d_out;

  char* ws = (char*)d_ws;
  float* wx = (float*)ws;                                   // 8 MB
  float* s1 = (float*)(ws + (8 << 20));                     // 64 KB
  float* s2 = (float*)(ws + (8 << 20) + (64 << 10));        // 64 KB

  gemm_wx<<<MROWS / 16, 256, 0, stream>>>(x_n, W_n, b_n, a_v, wx, s1, s2);
  attn_out<<<NBATCH * NFEAT, 256, 0, stream>>>(edge, bias_n, wx, s1, s2, out);
}

// Round 3
// 304.249 us; speedup vs baseline: 1.1940x; 1.0315x over previous
//
#include <hip/hip_runtime.h>

// FeatureAttentionLayer: B=64, NF=256, W=128, E=128, K=32 — ALL FP32.
#define NFEAT 256
#define TK    32
#define WIN   128
#define EMB   128
#define NBATCH 64
#define ALPHA 0.2f
#define MROWS (NBATCH * NFEAT)   // 16384 rows of Wx

__device__ __forceinline__ float lrelu(float x) { return x > 0.f ? x : ALPHA * x; }

// ---------------------------------------------------------------------------
// Kernel 1: Wx = x @ W + b  (M=16384, K=128, N=128), fp32 VALU.
// (reverted verbatim to the R0 32-row version — twice-validated at ~312 µs;
//  R2's 16-row variant was neutral, so keep the proven one)
// ---------------------------------------------------------------------------
__global__ __launch_bounds__(256) void gemm_wx(
    const float* __restrict__ x,      // 16384 x 128
    const float* __restrict__ W,      // 128 x 128 (row-major [k][n])
    const float* __restrict__ bn,     // 128
    const float* __restrict__ avec,   // 256
    float* __restrict__ wx,           // out: 16384 x 128
    float* __restrict__ s1, float* __restrict__ s2) {
  __shared__ float xT[WIN][36];      // [k][r], padded
  int t = threadIdx.x;
  int rows0 = blockIdx.x * 32;

  // ---- stage x tile transposed: thread t -> row r=t>>3, cols (t&7)*16..+15
  {
    int r = t >> 3, jc = t & 7;
    const float4* src = (const float4*)(x + (long)(rows0 + r) * WIN + jc * 16);
#pragma unroll
    for (int u = 0; u < 4; ++u) {
      float4 v = src[u];
      int c = jc * 16 + u * 4;
      xT[c + 0][r] = v.x; xT[c + 1][r] = v.y; xT[c + 2][r] = v.z; xT[c + 3][r] = v.w;
    }
  }
  __syncthreads();

  int g = t >> 5, ct = t & 31;
  int r0 = g * 4;                    // local rows r0..r0+3
  int c0 = ct * 4;                   // cols c0..c0+3

  float acc[4][4];
#pragma unroll
  for (int i = 0; i < 4; ++i)
#pragma unroll
    for (int j = 0; j < 4; ++j) acc[i][j] = 0.f;

#pragma unroll 4
  for (int k = 0; k < WIN; ++k) {
    float4 xv = *(const float4*)&xT[k][r0];
    float4 wv = *(const float4*)(W + k * EMB + c0);
    acc[0][0] += xv.x * wv.x; acc[0][1] += xv.x * wv.y; acc[0][2] += xv.x * wv.z; acc[0][3] += xv.x * wv.w;
    acc[1][0] += xv.y * wv.x; acc[1][1] += xv.y * wv.y; acc[1][2] += xv.y * wv.z; acc[1][3] += xv.y * wv.w;
    acc[2][0] += xv.z * wv.x; acc[2][1] += xv.z * wv.y; acc[2][2] += xv.z * wv.z; acc[2][3] += xv.z * wv.w;
    acc[3][0] += xv.w * wv.x; acc[3][1] += xv.w * wv.y; acc[3][2] += xv.w * wv.z; acc[3][3] += xv.w * wv.w;
  }

  // + b_n
  float4 bv = *(const float4*)(bn + c0);
#pragma unroll
  for (int i = 0; i < 4; ++i) {
    acc[i][0] += bv.x; acc[i][1] += bv.y; acc[i][2] += bv.z; acc[i][3] += bv.w;
  }

  // store Wx (coalesced float4 per 32-lane group)
#pragma unroll
  for (int i = 0; i < 4; ++i) {
    float4 o = make_float4(acc[i][0], acc[i][1], acc[i][2], acc[i][3]);
    *(float4*)(wx + (long)(rows0 + r0 + i) * EMB + c0) = o;
  }

  // s1/s2 epilogue
  float4 a1 = *(const float4*)(avec + c0);
  float4 a2 = *(const float4*)(avec + EMB + c0);
  float p1[4], p2[4];
#pragma unroll
  for (int i = 0; i < 4; ++i) {
    p1[i] = acc[i][0] * a1.x + acc[i][1] * a1.y + acc[i][2] * a1.z + acc[i][3] * a1.w;
    p2[i] = acc[i][0] * a2.x + acc[i][1] * a2.y + acc[i][2] * a2.z + acc[i][3] * a2.w;
  }
#pragma unroll
  for (int i = 0; i < 4; ++i) {
#pragma unroll
    for (int m = 1; m < 32; m <<= 1) {
      p1[i] += __shfl_xor(p1[i], m, 64);
      p2[i] += __shfl_xor(p2[i], m, 64);
    }
  }
  if (ct == 0) {
#pragma unroll
    for (int i = 0; i < 4; ++i) {
      s1[rows0 + r0 + i] = p1[i];
      s2[rows0 + r0 + i] = p2[i];
    }
  }
}

// ---------------------------------------------------------------------------
// Kernel 2: per (b,n): softmax over 32 k + streamed fp32 output.
// Phase 1 unchanged from the proven R0 version.
// R3 change (ONE delta): phase-2 lane mapping made transaction-DENSE.
//   Before: 16 lanes/row x 2 separate float4 ops at 32-B lane stride ->
//           every vmem instruction carried 16 B/lane with 16-B gaps
//           (half-utilized 64-B requests on BOTH the wx reads and the
//           256-MiB out stream).
//   Now:    32 lanes/row x 1 float4, 4 passes over k -> each instruction
//           is a fully-dense contiguous 512-B segment per half-wave.
// ---------------------------------------------------------------------------
__global__ __launch_bounds__(256) void attn_out(
    const int* __restrict__ edge,      // row 0 of edge_indices: 256*32 ints
    const float* __restrict__ biasn,   // 256*32
    const float* __restrict__ wx,      // 16384 x 128
    const float* __restrict__ s1, const float* __restrict__ s2,
    float* __restrict__ out) {
  __shared__ float att[TK];
  __shared__ int nbrS[TK];
  int bidx = blockIdx.x;
  int b = bidx >> 8, n = bidx & 255;
  int tid = threadIdx.x;

  if (tid < TK) {
    int k = tid;
    nbrS[k] = edge[n * TK + k];
    float v;
    if (k < 16) {
      v = s1[b * NFEAT + n] + s2[b * NFEAT + n];
    } else {
      int j0 = 2 * k - 32;
      int r0 = edge[n * TK + j0];
      int r1 = edge[n * TK + j0 + 1];
      v = s1[b * NFEAT + r0] + s2[b * NFEAT + r1];
    }
    v = lrelu(v);
    float bb = biasn[n * TK + k];
    if (bb != bb) bb = 0.f;            // nan_to_num
    v += bb;
    float mx = v;
#pragma unroll
    for (int m = 1; m < 32; m <<= 1) mx = fmaxf(mx, __shfl_xor(mx, m, 64));
    float ex = __expf(v - mx);
    float sum = ex;
#pragma unroll
    for (int m = 1; m < 32; m <<= 1) sum += __shfl_xor(sum, m, 64);
    att[k] = ex / sum;
  }
  __syncthreads();

  // 32 threads per k-row, one dense float4 each; 4 passes over k.
  int kq = tid >> 5;                   // 0..7
  int c  = (tid & 31) * 4;             // dense: 32 lanes x 16 B = 512 B
#pragma unroll
  for (int p = 0; p < 4; ++p) {
    int k = kq + p * 8;
    long row = (long)b * NFEAT + nbrS[k];
    float ak = att[k];
    float4 v = *(const float4*)(wx + row * EMB + c);
    float4 o = make_float4(lrelu(ak * v.x), lrelu(ak * v.y),
                           lrelu(ak * v.z), lrelu(ak * v.w));
    *(float4*)(out + ((long)bidx * TK + k) * EMB + c) = o;
  }
}

extern "C" void kernel_launch(void* const* d_in, const int* in_sizes, int n_in,
                              void* d_out, int out_size, void* d_ws, size_t ws_size,
                              hipStream_t stream) {
  const float* x_n    = (const float*)d_in[0];
  // d_in[1] x_e: unused by reference
  const int*   edge   = (const int*)d_in[2];
  // d_in[3] all_embeddings: unused by reference
  const float* W_n    = (const float*)d_in[4];
  const float* b_n    = (const float*)d_in[5];
  const float* a_v    = (const float*)d_in[6];
  const float* bias_n = (const float*)d_in[7];
  float* out = (float*)d_out;

  char* ws = (char*)d_ws;
  float* wx = (float*)ws;                                   // 8 MB
  float* s1 = (float*)(ws + (8 << 20));                     // 64 KB
  float* s2 = (float*)(ws + (8 << 20) + (64 << 10));        // 64 KB

  gemm_wx<<<MROWS / 32, 256, 0, stream>>>(x_n, W_n, b_n, a_v, wx, s1, s2);
  attn_out<<<NBATCH * NFEAT, 256, 0, stream>>>(edge, bias_n, wx, s1, s2, out);
}